// Round 2
// baseline (1985.522 us; speedup 1.0000x reference)
//
#include <hip/hip_runtime.h>
#include <hip/hip_bf16.h>

#define S_LEN   64
#define N_BATCH 65536
#define R_DIM   128
#define EMB_DIM 64
#define OUT_DIM 5
#define BN      64   // batch rows per block
#define NW      8    // waves per block

typedef unsigned short u16;
typedef unsigned short u16x8 __attribute__((ext_vector_type(8)));
typedef __bf16 bf16x8 __attribute__((ext_vector_type(8)));
typedef float f32x4 __attribute__((ext_vector_type(4)));

__device__ __forceinline__ u16 f2bf(float f) {
  unsigned u = __builtin_bit_cast(unsigned, f);
  u += 0x7fffu + ((u >> 16) & 1u);          // round-to-nearest-even
  return (u16)(u >> 16);
}
__device__ __forceinline__ float bf2f(u16 v) {
  unsigned u = ((unsigned)v) << 16;
  return __builtin_bit_cast(float, u);
}
__device__ __forceinline__ f32x4 MFMA(u16x8 a, u16x8 b, f32x4 c) {
  return __builtin_amdgcn_mfma_f32_16x16x32_bf16(
      __builtin_bit_cast(bf16x8, a), __builtin_bit_cast(bf16x8, b), c, 0, 0, 0);
}
__device__ __forceinline__ float sigm(float x) {
  return __builtin_amdgcn_rcpf(1.0f + __expf(-x));
}
__device__ __forceinline__ float tanh_fast(float x) {
  // tanh(x) = 1 - 2/(exp(2x)+1); saturates correctly for large |x|
  return 1.0f - 2.0f * __builtin_amdgcn_rcpf(1.0f + __expf(2.0f * x));
}

__global__ __launch_bounds__(512, 2) void vlstm_kernel(
    const float* __restrict__ x,      // (S,N,2)
    const float* __restrict__ h0,     // (N,128)
    const float* __restrict__ c0,     // (N,128)
    const int*   __restrict__ pmask,  // (S,N)
    const float* __restrict__ Wemb,   // (64,2)
    const float* __restrict__ bemb,   // (64)
    const float* __restrict__ Wih,    // (512,64)
    const float* __restrict__ Whh,    // (512,128)
    const float* __restrict__ bih,    // (512)
    const float* __restrict__ bhh,    // (512)
    const float* __restrict__ Wout,   // (5,128)
    const float* __restrict__ bout,   // (5)
    float* __restrict__ out)          // outputs (S,N,5) | h_final (N,128) | c_final (N,128)
{
  // h: bf16, row stride 256B, XOR-swizzled (granule ^= (row&7)<<4) for conflict-free ds_read_b128
  __shared__ __align__(16) u16 h_sh[BN * 128];
  __shared__ __align__(16) u16 e_sh[BN * 64];   // bf16, row stride 128B, same swizzle
  __shared__ int   mask_sh[2][BN];              // double-buffered (phase D of step t vs A of t+1)
  __shared__ float wemb_sh[EMB_DIM * 2];
  __shared__ float bemb_sh[EMB_DIM];

  const int tid = threadIdx.x;
  const int w   = tid >> 6;        // wave 0..7
  const int ln  = tid & 63;
  const int lo  = ln & 15;         // MFMA col / A-row lane index
  const int hi  = ln >> 4;         // MFMA k-group / C-row group
  const int base = blockIdx.x * BN;
  const int gcb  = w * 16 + lo;    // this lane's feature/gate column within a 128-wide gate

  if (tid < EMB_DIM * 2) wemb_sh[tid] = Wemb[tid];
  if (tid < EMB_DIM)     bemb_sh[tid] = bemb[tid];

  // ---- one-time: weight fragments (bf16) resident in registers -------------
  u16x8 wih[4][2], whh[4][4], wout_f[4];
  float bias_g[4];
#pragma unroll
  for (int q = 0; q < 4; ++q) {
    const int gc = q * 128 + gcb;                 // gate row in W_ih/W_hh
    const float* wp = Wih + gc * 64 + hi * 8;
#pragma unroll
    for (int ks = 0; ks < 2; ++ks)
#pragma unroll
      for (int j = 0; j < 8; ++j) wih[q][ks][j] = f2bf(wp[ks * 32 + j]);
    const float* wq = Whh + gc * 128 + hi * 8;
#pragma unroll
    for (int ks = 0; ks < 4; ++ks)
#pragma unroll
      for (int j = 0; j < 8; ++j) whh[q][ks][j] = f2bf(wq[ks * 32 + j]);
    bias_g[q] = bih[gc] + bhh[gc];
  }
#pragma unroll
  for (int ks = 0; ks < 4; ++ks)
#pragma unroll
    for (int j = 0; j < 8; ++j)
      wout_f[ks][j] = (lo < OUT_DIM) ? f2bf(Wout[lo * 128 + ks * 32 + hi * 8 + j]) : (u16)0;
  const float bout_v = (lo < OUT_DIM) ? bout[lo] : 0.0f;

  // ---- one-time: stage h0 -> LDS (bf16, swizzled) --------------------------
  {
    const int row = tid >> 3;           // 0..63
    const int cb  = (tid & 7) * 16;     // 16 cols per thread
    const float* hp = h0 + (size_t)(base + row) * 128 + cb;
#pragma unroll
    for (int half = 0; half < 2; ++half) {
      u16x8 v;
#pragma unroll
      for (int j = 0; j < 8; ++j) v[j] = f2bf(hp[half * 8 + j]);
      const int byte = row * 256 + ((((cb + half * 8) * 2)) ^ ((row & 7) << 4));
      *(u16x8*)((char*)h_sh + byte) = v;
    }
  }
  // ---- one-time: c0 -> registers (C-layout: row=(hi*4+r), col=gcb) ---------
  float cst[4][4];
#pragma unroll
  for (int rt = 0; rt < 4; ++rt)
#pragma unroll
    for (int r = 0; r < 4; ++r)
      cst[rt][r] = c0[(size_t)(base + rt * 16 + hi * 4 + r) * 128 + gcb];

  __syncthreads();

  float* const out_seq = out;
  float* const out_h   = out + (size_t)S_LEN * N_BATCH * OUT_DIM;
  float* const out_c   = out_h + (size_t)N_BATCH * R_DIM;

  for (int t = 0; t < S_LEN; ++t) {
    // ---- phase A: embedding -> e_sh (bf16, swizzled); mask -> mask_sh -----
    {
      const int row = tid & 63;
      const int kb  = tid >> 6;    // == w : k-chunk kb*8..kb*8+7
      const float2 xv = *(const float2*)(x + ((size_t)t * N_BATCH + base + row) * 2);
      u16x8 ev;
#pragma unroll
      for (int j = 0; j < 8; ++j) {
        const int k = kb * 8 + j;
        float e = fmaf(xv.y, wemb_sh[2 * k + 1], fmaf(xv.x, wemb_sh[2 * k], bemb_sh[k]));
        ev[j] = f2bf(fmaxf(e, 0.0f));
      }
      const int byte = row * 128 + ((kb * 16) ^ ((row & 7) << 4));
      *(u16x8*)((char*)e_sh + byte) = ev;
      if (tid < BN) mask_sh[t & 1][tid] = pmask[(size_t)t * N_BATCH + base + tid];
    }
    __syncthreads();   // e/mask ready; prior phase-D h reads done

    // ---- phase B: gate MFMAs (acc init = bias) -----------------------------
    f32x4 acc[4][4];
#pragma unroll
    for (int rt = 0; rt < 4; ++rt)
#pragma unroll
      for (int q = 0; q < 4; ++q) {
        f32x4 b = {bias_g[q], bias_g[q], bias_g[q], bias_g[q]};
        acc[rt][q] = b;
      }
#pragma unroll
    for (int rt = 0; rt < 4; ++rt) {
      const int row = rt * 16 + lo;
      const int swz = (row & 7) << 4;
      const char* hrow = (const char*)h_sh + row * 256;
      const char* erow = (const char*)e_sh + row * 128;
      u16x8 ae0 = *(const u16x8*)(erow + ((hi * 16      ) ^ swz));
      u16x8 ae1 = *(const u16x8*)(erow + ((hi * 16 +  64) ^ swz));
      u16x8 ah0 = *(const u16x8*)(hrow + ((hi * 16      ) ^ swz));
      u16x8 ah1 = *(const u16x8*)(hrow + ((hi * 16 +  64) ^ swz));
      u16x8 ah2 = *(const u16x8*)(hrow + ((hi * 16 + 128) ^ swz));
      u16x8 ah3 = *(const u16x8*)(hrow + ((hi * 16 + 192) ^ swz));
#pragma unroll
      for (int q = 0; q < 4; ++q) {
        f32x4 a = acc[rt][q];
        a = MFMA(ae0, wih[q][0], a);
        a = MFMA(ae1, wih[q][1], a);
        a = MFMA(ah0, whh[q][0], a);
        a = MFMA(ah1, whh[q][1], a);
        a = MFMA(ah2, whh[q][2], a);
        a = MFMA(ah3, whh[q][3], a);
        acc[rt][q] = a;
      }
    }
    __syncthreads();   // all h_sh reads complete before updates

    // ---- phase C: nonlinearities + masked state update ---------------------
#pragma unroll
    for (int rt = 0; rt < 4; ++rt) {
#pragma unroll
      for (int r = 0; r < 4; ++r) {
        const int row = rt * 16 + hi * 4 + r;
        const float iv = sigm(acc[rt][0][r]);
        const float fv = sigm(acc[rt][1][r]);
        const float gv = tanh_fast(acc[rt][2][r]);
        const float ov = sigm(acc[rt][3][r]);
        const float cn = fmaf(fv, cst[rt][r], iv * gv);
        const float hn = ov * tanh_fast(cn);
        if (mask_sh[t & 1][row]) {
          cst[rt][r] = cn;
          const int byte = row * 256 + ((gcb * 2) ^ ((row & 7) << 4));
          *(u16*)((char*)h_sh + byte) = f2bf(hn);
        }
      }
    }
    __syncthreads();   // h_sh now holds h_t

    // ---- phase D: output projection (waves 0..3, one row-tile each) --------
    if (w < 4) {
      const int rt  = w;
      const int row = rt * 16 + lo;
      const int swz = (row & 7) << 4;
      const char* hrow = (const char*)h_sh + row * 256;
      u16x8 a0 = *(const u16x8*)(hrow + ((hi * 16      ) ^ swz));
      u16x8 a1 = *(const u16x8*)(hrow + ((hi * 16 +  64) ^ swz));
      u16x8 a2 = *(const u16x8*)(hrow + ((hi * 16 + 128) ^ swz));
      u16x8 a3 = *(const u16x8*)(hrow + ((hi * 16 + 192) ^ swz));
      f32x4 oa = {bout_v, bout_v, bout_v, bout_v};
      oa = MFMA(a0, wout_f[0], oa);
      oa = MFMA(a1, wout_f[1], oa);
      oa = MFMA(a2, wout_f[2], oa);
      oa = MFMA(a3, wout_f[3], oa);
      if (lo < OUT_DIM) {
#pragma unroll
        for (int r = 0; r < 4; ++r) {
          const int orow = rt * 16 + hi * 4 + r;
          const float val = mask_sh[t & 1][orow] ? oa[r] : 0.0f;
          out_seq[((size_t)t * N_BATCH + base + orow) * OUT_DIM + lo] = val;
        }
      }
    }
  }

  // ---- finals: h from LDS (bf16->f32), c from registers --------------------
  {
    const int row = tid >> 3;
    const int cb  = (tid & 7) * 16;
    float* hp = out_h + (size_t)(base + row) * 128 + cb;
#pragma unroll
    for (int half = 0; half < 2; ++half) {
      const int byte = row * 256 + ((((cb + half * 8) * 2)) ^ ((row & 7) << 4));
      u16x8 v = *(const u16x8*)((const char*)h_sh + byte);
#pragma unroll
      for (int j = 0; j < 8; ++j) hp[half * 8 + j] = bf2f(v[j]);
    }
  }
#pragma unroll
  for (int rt = 0; rt < 4; ++rt)
#pragma unroll
    for (int r = 0; r < 4; ++r)
      out_c[(size_t)(base + rt * 16 + hi * 4 + r) * 128 + gcb] = cst[rt][r];
}

extern "C" void kernel_launch(void* const* d_in, const int* in_sizes, int n_in,
                              void* d_out, int out_size, void* d_ws, size_t ws_size,
                              hipStream_t stream) {
  (void)in_sizes; (void)n_in; (void)out_size; (void)d_ws; (void)ws_size;
  const int grid = N_BATCH / BN;   // 1024 blocks
  vlstm_kernel<<<grid, 512, 0, stream>>>(
      (const float*)d_in[0], (const float*)d_in[1], (const float*)d_in[2],
      (const int*)d_in[3],
      (const float*)d_in[4], (const float*)d_in[5],
      (const float*)d_in[6], (const float*)d_in[7],
      (const float*)d_in[8], (const float*)d_in[9],
      (const float*)d_in[10], (const float*)d_in[11],
      (float*)d_out);
}